// Round 4
// baseline (234.995 us; speedup 1.0000x reference)
//
#include <hip/hip_runtime.h>
#include <hip/hip_bf16.h>

// LengthRegulator, single fused kernel (round 4 = round 3 + compile fix).
// xs [B=32, T=512, D=384] f32, durations [B=32, T=512] i32 in [0,8)
// out [B, T_out=4096, D] f32: phoneme rows repeated `duration` times,
// left-aligned, zero-padded to T_out.
//
// Roofline: 192 MiB write + ~25 MiB read -> ~36 us at 6.3 TB/s.
// Changes vs R2: shfl-based scan (3 barriers vs ~20), valid/pad loop split
// (pad = pure zero stream, ~56% of output), nontemporal stores, no div in
// the copy loop. R4 fix: clang ext_vector float4 for nontemporal builtins
// (HIP_vector_type float4 is a class -> builtin rejects it).

#define B    32
#define T    512
#define D    384
#define TOUT 4096           // T * DUR_MAX
#define CH   (D / 4)        // 96 float4 chunks per frame
#define F    128            // output frames per block
#define NT   512            // threads per block
#define ITEMS (F * CH)      // 12288 float4 per block

typedef float f4 __attribute__((ext_vector_type(4)));

__global__ __launch_bounds__(NT) void k_lenreg(const f4* __restrict__ xs4,
                                               const int* __restrict__ dur,
                                               f4* __restrict__ out4) {
    __shared__ int s_cum[T];
    __shared__ int s_idx[F];
    __shared__ int s_wsum[NT / 64];
    __shared__ int s_red[NT / 64];
    const int b      = blockIdx.y;
    const int frame0 = blockIdx.x * F;
    const int tid    = threadIdx.x;
    const int lane   = tid & 63;
    const int w      = tid >> 6;

    // ---- inclusive scan of this row's durations: shfl within wave, LDS combine ----
    int sum = dur[b * T + tid];
    #pragma unroll
    for (int off = 1; off < 64; off <<= 1) {
        int v = __shfl_up(sum, off);
        if (lane >= off) sum += v;
    }
    if (lane == 63) s_wsum[w] = sum;
    __syncthreads();
    int prefix = 0, rowtot = 0;
    #pragma unroll
    for (int i = 0; i < NT / 64; ++i) {
        int v = s_wsum[i];
        rowtot += v;
        if (i < w) prefix += v;
    }
    int cum = sum + prefix;

    // ---- rare path: row total == 0 -> check global total (torch edge case) ----
    if (rowtot == 0) {                      // block-uniform branch
        int g = 0;
        for (int i = tid; i < B * T; i += NT) g += dur[i];
        #pragma unroll
        for (int o = 32; o > 0; o >>= 1) g += __shfl_down(g, o);
        if (lane == 0) s_red[w] = g;
        __syncthreads();
        int tot = 0;
        #pragma unroll
        for (int i = 0; i < NT / 64; ++i) tot += s_red[i];
        if (tot == 0) cum = tid + 1;        // all d -> 1: cum[t] = t+1
    }
    s_cum[tid] = cum;
    __syncthreads();

    const int last = s_cum[T - 1];
    int nvalid = last - frame0;
    nvalid = nvalid < 0 ? 0 : (nvalid > F ? F : nvalid);
    const int vitems = nvalid * CH;

    // ---- per-frame phoneme index via branchless upper_bound (valid frames only) ----
    if (tid < nvalid) {
        int t = frame0 + tid;
        int idx = 0;                        // idx = #elements <= t (side='right')
        #pragma unroll
        for (int step = T / 2; step > 0; step >>= 1)
            if (s_cum[idx + step - 1] <= t) idx += step;
        s_idx[tid] = idx < T - 1 ? idx : T - 1;
    }
    __syncthreads();

    const size_t obase = ((size_t)b * TOUT + frame0) * CH;
    const size_t ibase = (size_t)b * T * CH;

    // ---- valid region: gather + stream; f,c tracked incrementally (no div) ----
    {
        int f = tid / CH;                   // one magic-div, outside the loop
        int c = tid - f * CH;
        for (int item = tid; item < vitems; item += NT) {
            f4 v = xs4[ibase + (size_t)s_idx[f] * CH + c];
            __builtin_nontemporal_store(v, out4 + obase + item);
            f += NT / CH;                   // 512 = 5*96 + 32
            c += NT - (NT / CH) * CH;
            if (c >= CH) { c -= CH; ++f; }
        }
    }
    // ---- pad region: pure zero stream (no LDS, no branches) ----
    {
        const f4 z = (f4){0.f, 0.f, 0.f, 0.f};
        for (int item = vitems + tid; item < ITEMS; item += NT)
            __builtin_nontemporal_store(z, out4 + obase + item);
    }
}

extern "C" void kernel_launch(void* const* d_in, const int* in_sizes, int n_in,
                              void* d_out, int out_size, void* d_ws, size_t ws_size,
                              hipStream_t stream) {
    const float* xs  = (const float*)d_in[0];
    const int*   dur = (const int*)d_in[1];
    float*       out = (float*)d_out;

    dim3 grid(TOUT / F, B);                 // 32 x 32 = 1024 blocks
    k_lenreg<<<grid, NT, 0, stream>>>((const f4*)xs, dur, (f4*)out);
}